// Round 6
// baseline (220.497 us; speedup 1.0000x reference)
//
#include <hip/hip_runtime.h>
#include <stdint.h>

#define BS 8192
#define DD 128
#define SPLIT 16  // j-slices per 64-row block; grid = 128*SPLIT = 2048 blocks

typedef __attribute__((ext_vector_type(8))) short short8;
typedef __attribute__((ext_vector_type(4))) float float4v;

#if __has_builtin(__builtin_amdgcn_exp2f)
#define EXP2(x) __builtin_amdgcn_exp2f(x)
#else
#define EXP2(x) exp2f(x)
#endif

__device__ __forceinline__ float bf2f(short s) {
  union { unsigned u; float f; } c;
  c.u = ((unsigned)(unsigned short)s) << 16;
  return c.f;
}
__device__ __forceinline__ short f2bf(float f) {
  union { float f; unsigned u; } c; c.f = f;
  unsigned u = c.u + 0x7FFFu + ((c.u >> 16) & 1u);
  return (short)(u >> 16);
}

// K1: normalize rows (f32 + packed-bf16 copies), per-class column sums, counts,
// f32 label mask mf[], zero-init of Zr/Ur/Vr/out (all stream-ordered before use).
__global__ __launch_bounds__(256) void k_norm(const float* __restrict__ data,
                                              const int* __restrict__ label,
                                              unsigned int* __restrict__ xnb32,
                                              float* __restrict__ xnf,
                                              float* __restrict__ gh,
                                              int* __restrict__ cnt,
                                              float* __restrict__ Zr,
                                              float* __restrict__ Ur,
                                              float* __restrict__ Vr,
                                              float* __restrict__ mf,
                                              float* __restrict__ out) {
  __shared__ float sh[256];
  __shared__ int shc[2];
  int tid = threadIdx.x, wave = tid >> 6, lane = tid & 63;
  if (tid < 2) shc[tid] = 0;
  sh[tid] = 0.f;
  if (tid < 32) {  // zero this block's accumulator slice (pre-poisoned 0xAA)
    int row = blockIdx.x * 32 + tid;
    Zr[row] = 0.f; Ur[row] = 0.f; Vr[row] = 0.f;
    mf[row] = (label[row] == 0) ? 1.f : 0.f;
  }
  if (blockIdx.x == 0 && tid == 0) out[0] = 0.f;
  __syncthreads();
  float a00 = 0.f, a01 = 0.f, a10 = 0.f, a11 = 0.f;
  int c0 = 0, c1 = 0;
  int rbase = blockIdx.x * 32 + wave * 8;
  for (int r = 0; r < 8; ++r) {
    int row = rbase + r;
    float2 v = *(const float2*)&data[row * DD + lane * 2];
    float ss = v.x * v.x + v.y * v.y;
    for (int off = 32; off; off >>= 1) ss += __shfl_xor(ss, off);
    float rn = 1.f / fmaxf(sqrtf(ss), 1e-12f);  // F.normalize eps clamp
    float x0 = v.x * rn, x1 = v.y * rn;
    *(float2*)&xnf[row * DD + lane * 2] = make_float2(x0, x1);
    unsigned int pk = (unsigned int)(unsigned short)f2bf(x0) |
                      ((unsigned int)(unsigned short)f2bf(x1) << 16);
    xnb32[row * 64 + lane] = pk;
    int lab = label[row];  // wave-uniform
    if (lab == 0) { a00 += x0; a01 += x1; c0++; }
    else          { a10 += x0; a11 += x1; c1++; }
  }
  atomicAdd(&sh[2 * lane], a00);
  atomicAdd(&sh[2 * lane + 1], a01);
  atomicAdd(&sh[128 + 2 * lane], a10);
  atomicAdd(&sh[128 + 2 * lane + 1], a11);
  if (lane == 0) { atomicAdd(&shc[0], c0); atomicAdd(&shc[1], c1); }
  __syncthreads();
  atomicAdd(&gh[tid], sh[tid]);
  if (tid < 2) atomicAdd(&cnt[tid], shc[tid]);
}

// K3: no-LDS, explicit depth-2 REGISTER prefetch pipeline.
// R4 post-mortem: no-LDS failed because the compiler kept VGPR=60 and ~1 iter of
// loads in flight (serial L2-latency chains). R2/R3/R5: every LDS+barrier variant
// is pinned at 41-44us — the vmcnt(0)+s_barrier drain is structural. Here each
// wave loads its own B fragments (16 cols x 128, 4x global_load_dwordx4 — all 4
// waves of a block walk the same 4KB window, so L1 serves most of it) with loads
// for iteration j+2 issued before computing iteration j: >=8 dwordx4 in flight
// per wave, no barriers anywhere. __launch_bounds__(256,4) caps VGPR at 128 so
// 4 waves/SIMD remain resident.
struct BFrag { short8 b[4]; float m; };

__global__ __launch_bounds__(256, 4) void k_main(const unsigned short* __restrict__ xnb,
                                                 const int* __restrict__ label,
                                                 const float* __restrict__ mf,
                                                 const float* __restrict__ scale,
                                                 float* __restrict__ Zr,
                                                 float* __restrict__ Ur,
                                                 float* __restrict__ Vr) {
  int tid = threadIdx.x, wave = tid >> 6, lane = tid & 63;
  int quad = lane >> 4, col = lane & 15;
  int rb = blockIdx.x / SPLIT, sl = blockIdx.x % SPLIT;
  float se2 = __expf(scale[0]) * 1.4426950408889634f;  // exp(scale)*log2(e)

  // A fragment: A[m=lane&15][k=quad*8+i], ktiles t=0..3 cover K=128
  int arow = rb * 64 + wave * 16 + col;
  const short* ap = (const short*)xnb + (size_t)arow * DD;
  short8 afrag[4];
#pragma unroll
  for (int t = 0; t < 4; ++t) {
    short8 a = *(const short8*)(ap + t * 32 + quad * 8);
#pragma unroll
    for (int i = 0; i < 8; ++i) a[i] = f2bf(bf2f(a[i]) * se2);
    afrag[t] = a;
  }
  int labI[4];
#pragma unroll
  for (int r = 0; r < 4; ++r) labI[r] = label[rb * 64 + wave * 16 + quad * 4 + r];

  float Z[4] = {}, U[4] = {}, V0[4] = {};

  const short* xs = (const short*)xnb;
  int jbase = sl * (BS / SPLIT), jend = jbase + (BS / SPLIT);

  // loader: B fragments for 16-col tile at j (per lane: row j+col, chunks t*32+quad*8)
  auto loadB = [&](int j) {
    BFrag f;
    const short* bp = xs + (size_t)(j + col) * DD + quad * 8;
    f.b[0] = *(const short8*)(bp);
    f.b[1] = *(const short8*)(bp + 32);
    f.b[2] = *(const short8*)(bp + 64);
    f.b[3] = *(const short8*)(bp + 96);
    f.m = mf[j + col];
    return f;
  };

  BFrag f0 = loadB(jbase);
  BFrag f1 = loadB(jbase + 16);
#pragma unroll 4
  for (int j = jbase; j < jend; j += 16) {
    int jn = (j + 32 < jend) ? (j + 32) : jbase;  // clamp: dummy reload on tail
    BFrag fn = loadB(jn);                          // depth-2 prefetch, in flight...
    float4v c = {0.f, 0.f, 0.f, 0.f};              // ...over this tile's compute
    c = __builtin_amdgcn_mfma_f32_16x16x32_bf16(afrag[0], f0.b[0], c, 0, 0, 0);
    c = __builtin_amdgcn_mfma_f32_16x16x32_bf16(afrag[1], f0.b[1], c, 0, 0, 0);
    c = __builtin_amdgcn_mfma_f32_16x16x32_bf16(afrag[2], f0.b[2], c, 0, 0, 0);
    c = __builtin_amdgcn_mfma_f32_16x16x32_bf16(afrag[3], f0.b[3], c, 0, 0, 0);
    float m0 = f0.m;
#pragma unroll
    for (int r = 0; r < 4; ++r) {  // C/D: col=lane&15, row=quad*4+r (m89)
      float l = c[r], e = EXP2(l);  // log2-domain: l2 <= 20.6 -> e <= 1.6e6, fp32-safe
      Z[r] += e; U[r] += e * l; V0[r] += m0 * e;
    }
    f0 = f1; f1 = fn;  // rotate pipeline
  }

  // reduce across the 16 column-lanes sharing each row
#pragma unroll
  for (int r = 0; r < 4; ++r)
#pragma unroll
    for (int off = 1; off < 16; off <<= 1) {
      Z[r] += __shfl_xor(Z[r], off);
      U[r] += __shfl_xor(U[r], off);
      V0[r] += __shfl_xor(V0[r], off);
    }
  if (col == 0) {
#pragma unroll
    for (int r = 0; r < 4; ++r) {
      int row = rb * 64 + wave * 16 + quad * 4 + r;
      float v = (labI[r] == 0) ? V0[r] : (Z[r] - V0[r]);  // same-class sum-exp
      atomicAdd(&Zr[row], Z[r]);
      atomicAdd(&Ur[row], U[r] * 0.6931471805599453f);  // log2-domain -> nats
      atomicAdd(&Vr[row], v);
    }
  }
}

// K4: per-row loss. S,T via closed-form dots with class sums; M and log(Zq) cancel.
__global__ __launch_bounds__(256) void k_final(const float* __restrict__ xnf,
                                               const int* __restrict__ label,
                                               const float* __restrict__ scale,
                                               const float* __restrict__ gh,
                                               const int* __restrict__ cnt,
                                               const float* __restrict__ Zr,
                                               const float* __restrict__ Ur,
                                               const float* __restrict__ Vr,
                                               float* __restrict__ out) {
  __shared__ float bsum[4];
  int tid = threadIdx.x, wave = tid >> 6, lane = tid & 63;
  float se = __expf(scale[0]);
  float h0a = gh[2 * lane], h0b = gh[2 * lane + 1];
  float h1a = gh[128 + 2 * lane], h1b = gh[128 + 2 * lane + 1];
  float ga = h0a + h1a, gb = h0b + h1b;  // g = h0 + h1
  float c0 = (float)cnt[0], c1 = (float)cnt[1];
  float local = 0.f;
  int rbase = blockIdx.x * 32 + wave * 8;
  for (int r = 0; r < 8; ++r) {
    int row = rbase + r;
    float2 x = *(const float2*)&xnf[row * DD + lane * 2];
    int lab = label[row];
    float sg = x.x * ga + x.y * gb;
    float sh_ = (lab == 0) ? (x.x * h0a + x.y * h0b) : (x.x * h1a + x.y * h1b);
    for (int off = 32; off; off >>= 1) {
      sg += __shfl_xor(sg, off);
      sh_ += __shfl_xor(sh_, off);
    }
    if (lane == 0) {
      float cc = (lab == 0) ? c0 : c1;
      float a = __expf(1.f / cc);
      float Zq = cc * a + ((float)BS - cc);
      float S = se * sg, T = se * sh_;
      float Z = Zr[row], U = Ur[row], V = Vr[row];
      // loss_i = a/Zq - (S+(a-1)T)/Zq + U/Z - V/(c*Z)   (M_i, log Zq cancelled)
      local += a / Zq - (S + (a - 1.f) * T) / Zq + U / Z - V / (cc * Z);
    }
  }
  if (lane == 0) bsum[wave] = local;
  __syncthreads();
  if (tid == 0) {
    float s = bsum[0] + bsum[1] + bsum[2] + bsum[3];
    atomicAdd(out, s * (0.5f / (float)BS));
  }
}

extern "C" void kernel_launch(void* const* d_in, const int* in_sizes, int n_in,
                              void* d_out, int out_size, void* d_ws, size_t ws_size,
                              hipStream_t stream) {
  const float* data = (const float*)d_in[0];
  const float* scale = (const float*)d_in[1];
  const int* label = (const int*)d_in[2];
  char* ws = (char*)d_ws;
  // ws layout (bytes):
  //   0        xnb  bf16[8192*128]   2 MB
  //   2097152  xnf  f32 [8192*128]   4 MB
  //   6291456  Zr   f32 [8192]
  //   6324224  Ur   f32 [8192]
  //   6356992  Vr   f32 [8192]
  //   6389760  gh   f32 [256]  (h0[128], h1[128])
  //   6390784  cnt  int [2]
  //   6390800  mf   f32 [8192]  (label==0 ? 1.0 : 0.0)
  unsigned short* xnb = (unsigned short*)ws;
  unsigned int* xnb32 = (unsigned int*)ws;
  float* xnf = (float*)(ws + 2097152);
  float* Zr = (float*)(ws + 6291456);
  float* Ur = (float*)(ws + 6324224);
  float* Vr = (float*)(ws + 6356992);
  float* gh = (float*)(ws + 6389760);
  int* cnt = (int*)(ws + 6390784);
  float* mf = (float*)(ws + 6390800);

  // gh+cnt only (1032 B); Zr/Ur/Vr/mf + d_out are initialized inside k_norm
  hipMemsetAsync(ws + 6389760, 0, 1032, stream);

  k_norm<<<256, 256, 0, stream>>>(data, label, xnb32, xnf, gh, cnt, Zr, Ur, Vr, mf,
                                  (float*)d_out);
  k_main<<<128 * SPLIT, 256, 0, stream>>>(xnb, label, mf, scale, Zr, Ur, Vr);
  k_final<<<256, 256, 0, stream>>>(xnf, label, scale, gh, cnt, Zr, Ur, Vr, (float*)d_out);
}